// Round 10
// baseline (362.634 us; speedup 1.0000x reference)
//
#include <hip/hip_runtime.h>
#include <math.h>

#define T_TOK 65536
#define K_CODE 1024
#define E_DIM 64
#define DECAYF 0.99f
#define EPSF 1e-5f
#define MARG2 1.5e-4f  // 2*M: bound on 2*|dist_mfma - dist_emul| with ~2.5x headroom

typedef __attribute__((ext_vector_type(8))) short short8;
typedef __attribute__((ext_vector_type(4))) float fx4;

// --- exact-rounding helpers: block ffp-contract=fast fusion ---
__device__ __forceinline__ float mul_nf(float a, float b) {
#pragma clang fp contract(off)
    return a * b;
}
__device__ __forceinline__ float add_nf(float a, float b) {
#pragma clang fp contract(off)
    return a + b;
}
__device__ __forceinline__ float sub_nf(float a, float b) {
#pragma clang fp contract(off)
    return a - b;
}

__device__ __forceinline__ unsigned short bf16_rn(float f) {
    union { float f; unsigned u; } v; v.f = f;
    unsigned r = v.u + 0x7fffu + ((v.u >> 16) & 1u);
    return (unsigned short)(r >> 16);
}
__device__ __forceinline__ float bf16_up(unsigned short h) {
    union { unsigned u; float f; } v; v.u = ((unsigned)h) << 16;
    return v.f;
}

// numpy pairwise_sum for n=64 of elementwise squares (products rounded
// separately, 8 strided accumulators, fixed combine tree) — streams from
// the given pointer, no local array.
__device__ __forceinline__ float np_sq_sum64(const float* v) {
    float r[8];
#pragma unroll
    for (int j = 0; j < 8; ++j) r[j] = mul_nf(v[j], v[j]);
#pragma unroll
    for (int i = 8; i < 64; i += 8) {
#pragma unroll
        for (int j = 0; j < 8; ++j) r[j] = add_nf(r[j], mul_nf(v[i + j], v[i + j]));
    }
    float s01 = add_nf(r[0], r[1]);
    float s23 = add_nf(r[2], r[3]);
    float s45 = add_nf(r[4], r[5]);
    float s67 = add_nf(r[6], r[7]);
    return add_nf(add_nf(s01, s23), add_nf(s45, s67));
}

// rows [0,T): np-exact ||x||^2 per token. rows [T, T+K): np-exact wnorm +
// bf16 hi/lo split of the code row.
__global__ __launch_bounds__(256) void prep_kernel(const float* __restrict__ z_e,
                                                   const float* __restrict__ embed,
                                                   float* __restrict__ xn_out,
                                                   float* __restrict__ wnorm_out,
                                                   unsigned short* __restrict__ whi,
                                                   unsigned short* __restrict__ wlo) {
    int row = blockIdx.x * 256 + threadIdx.x;
    if (row < T_TOK) {
        xn_out[row] = np_sq_sum64(z_e + (size_t)row * E_DIM);
    } else {
        int k = row - T_TOK;
        const float* w = embed + (size_t)k * E_DIM;
        wnorm_out[k] = np_sq_sum64(w);
#pragma unroll
        for (int i = 0; i < 64; ++i) {
            float e = w[i];
            unsigned short h = bf16_rn(e);
            whi[(size_t)k * 64 + i] = h;
            wlo[(size_t)k * 64 + i] = bf16_rn(e - bf16_up(h));
        }
    }
}

// Block = 256 thr = 4 waves; wave owns one 16-token M-tile, scans all 1024
// codes as 64 16-code N-tiles. 3-pass bf16-split MFMA (hi*hi + lo*hi + hi*lo)
// into one fp32 acc; dist via the SAME np-exact xn/wn and same final rounding
// ops as the emulated path, so |dist_mfma - dist_emul| <= ~8e-5 < MARG2.
// Per token-slot tracks top-3 (m1,i1,m2,i2,m3); cross-lane shfl-merge; then:
//   m2-m1 > MARG2          -> i1 is provably the np argmin
//   m3-m1 > MARG2 >= m2-m1 -> exact-emulate {i1,i2} inline (verified chain)
//   else                   -> flag token for full exact rescan (epilogue)
// C/D layout (m89-verified): col=lane&15, row=(lane>>4)*4+reg.
// A layout: A[m=lane&15][k=(lane>>4)*8+j]; B[n=lane&15][k=(lane>>4)*8+j].
__global__ __launch_bounds__(256) void mfma_argmin_kernel(const float* __restrict__ z_e,
                                                          const float* __restrict__ embed,
                                                          const float* __restrict__ xn_ws,
                                                          const float* __restrict__ wnorm_ws,
                                                          const unsigned short* __restrict__ whi,
                                                          const unsigned short* __restrict__ wlo,
                                                          float* __restrict__ out_ind,
                                                          float* __restrict__ flags) {
    int lane = threadIdx.x & 63;
    int wave = threadIdx.x >> 6;
    int quad = lane >> 4;
    int lmod = lane & 15;
    int t0 = blockIdx.x * 64 + wave * 16;

    // A fragments: token = t0+lmod, dims q*32 + quad*8 + j; bf16 hi/lo built in-reg
    short8 ah[2], al[2];
#pragma unroll
    for (int q = 0; q < 2; ++q) {
        const float* xp = z_e + (size_t)(t0 + lmod) * E_DIM + q * 32 + quad * 8;
#pragma unroll
        for (int j = 0; j < 8; ++j) {
            float e = xp[j];
            unsigned short h = bf16_rn(e);
            ah[q][j] = (short)h;
            al[q][j] = (short)bf16_rn(e - bf16_up(h));
        }
    }

    // np-exact ||x||^2 for this lane's 4 C-row tokens
    fx4 xnv = *(const fx4*)(xn_ws + t0 + quad * 4);

    float m1[4], m2[4], m3[4];
    int i1[4], i2[4];
#pragma unroll
    for (int r = 0; r < 4; ++r) { m1[r] = m2[r] = m3[r] = INFINITY; i1[r] = i2[r] = 0; }

    for (int n = 0; n < 64; ++n) {
        size_t boff = (size_t)(n * 16 + lmod) * 64 + quad * 8;
        short8 bh0 = *(const short8*)(whi + boff);
        short8 bl0 = *(const short8*)(wlo + boff);
        short8 bh1 = *(const short8*)(whi + boff + 32);
        short8 bl1 = *(const short8*)(wlo + boff + 32);
        fx4 acc = {0.f, 0.f, 0.f, 0.f};
        acc = __builtin_amdgcn_mfma_f32_16x16x32_bf16(ah[0], bh0, acc, 0, 0, 0);
        acc = __builtin_amdgcn_mfma_f32_16x16x32_bf16(al[0], bh0, acc, 0, 0, 0);
        acc = __builtin_amdgcn_mfma_f32_16x16x32_bf16(ah[0], bl0, acc, 0, 0, 0);
        acc = __builtin_amdgcn_mfma_f32_16x16x32_bf16(ah[1], bh1, acc, 0, 0, 0);
        acc = __builtin_amdgcn_mfma_f32_16x16x32_bf16(al[1], bh1, acc, 0, 0, 0);
        acc = __builtin_amdgcn_mfma_f32_16x16x32_bf16(ah[1], bl1, acc, 0, 0, 0);

        float wn = wnorm_ws[n * 16 + lmod];
        int code = n * 16 + lmod;
#pragma unroll
        for (int r = 0; r < 4; ++r) {
            float d = acc[r];
            float dist = add_nf(sub_nf(xnv[r], d + d), wn);
            bool l1 = dist < m1[r], l2 = dist < m2[r], l3 = dist < m3[r];
            m3[r] = l2 ? m2[r] : (l3 ? dist : m3[r]);
            m2[r] = l1 ? m1[r] : (l2 ? dist : m2[r]);
            i2[r] = l1 ? i1[r] : (l2 ? code : i2[r]);
            m1[r] = l1 ? dist : m1[r];
            i1[r] = l1 ? code : i1[r];
        }
    }

    // merge sorted top-3 lists across the 16 lanes of each quad-group
#pragma unroll
    for (int s = 1; s < 16; s <<= 1) {
#pragma unroll
        for (int r = 0; r < 4; ++r) {
            float b1 = __shfl_xor(m1[r], s, 64);
            int bi1 = __shfl_xor(i1[r], s, 64);
            float b2 = __shfl_xor(m2[r], s, 64);
            int bi2 = __shfl_xor(i2[r], s, 64);
            float b3 = __shfl_xor(m3[r], s, 64);
            bool aw = m1[r] <= b1;                       // winner of firsts
            float w2 = aw ? m2[r] : b2; int wi2 = aw ? i2[r] : bi2;
            float w3 = aw ? m3[r] : b3;
            float l1v = aw ? b1 : m1[r]; int li1 = aw ? bi1 : i1[r];
            float l2v = aw ? b2 : m2[r];
            float n1 = aw ? m1[r] : b1; int ni1 = aw ? i1[r] : bi1;
            bool sw = w2 <= l1v;                          // winner's 2nd vs loser's 1st
            float n2 = sw ? w2 : l1v; int ni2 = sw ? wi2 : li1;
            float n3 = sw ? fminf(w3, l1v) : fminf(w2, l2v);
            m1[r] = n1; i1[r] = ni1; m2[r] = n2; i2[r] = ni2; m3[r] = n3;
        }
    }

    if (lmod == 0) {
#pragma unroll
        for (int r = 0; r < 4; ++r) {
            int token = t0 + quad * 4 + r;
            int I1 = i1[r], I2 = i2[r];
            float bi_f;
            if (m3[r] - m1[r] <= MARG2) {
                flags[token] = 1.0f;         // >=3 candidates: full exact rescan
                bi_f = (float)I1;
            } else if (m2[r] - m1[r] <= MARG2) {
                // exact pair: verified sequential-FMA chain for both candidates
                const float* xrow = z_e + (size_t)token * E_DIM;
                const float* wa = embed + (size_t)I1 * E_DIM;
                const float* wb = embed + (size_t)I2 * E_DIM;
                float da = 0.f, db = 0.f;
#pragma unroll
                for (int c = 0; c < 16; ++c) {
                    float4 xc = *(const float4*)(xrow + 4 * c);
                    float4 ac = *(const float4*)(wa + 4 * c);
                    float4 bc = *(const float4*)(wb + 4 * c);
                    da = __builtin_fmaf(xc.x, ac.x, da);
                    da = __builtin_fmaf(xc.y, ac.y, da);
                    da = __builtin_fmaf(xc.z, ac.z, da);
                    da = __builtin_fmaf(xc.w, ac.w, da);
                    db = __builtin_fmaf(xc.x, bc.x, db);
                    db = __builtin_fmaf(xc.y, bc.y, db);
                    db = __builtin_fmaf(xc.z, bc.z, db);
                    db = __builtin_fmaf(xc.w, bc.w, db);
                }
                float dista = add_nf(sub_nf(xnv[r], da + da), wnorm_ws[I1]);
                float distb = add_nf(sub_nf(xnv[r], db + db), wnorm_ws[I2]);
                int bi = (distb < dista || (distb == dista && I2 < I1)) ? I2 : I1;
                bi_f = (float)bi;
            } else {
                bi_f = (float)I1;            // provably the np argmin
            }
            out_ind[token] = bi_f;
        }
    }
}

// Per block: 64 tokens, 4 waves x 16 tokens. For flagged tokens the owning
// wave does the full exact rescan (lane c handles codes c+64j, verified
// chain, np-first-index tie merge). Then z_q / straight-through / diff and
// the coalesced row-atomic EMA scatter.
__global__ __launch_bounds__(256) void epilogue_kernel(const float* __restrict__ z_e,
                                                       const float* __restrict__ embed,
                                                       const float* __restrict__ xn_ws,
                                                       const float* __restrict__ wnorm_ws,
                                                       float* __restrict__ out_ind,
                                                       const float* __restrict__ flags,
                                                       float* __restrict__ out_zq,
                                                       float* __restrict__ diff_acc,
                                                       float* __restrict__ esum_rep,
                                                       float* __restrict__ onehot_rep,
                                                       int rep_mask) {
    __shared__ float xs[4][64];
    int lane = threadIdx.x & 63;
    int wave = threadIdx.x >> 6;
    int rep = blockIdx.x & rep_mask;
    float* esum = esum_rep + (size_t)rep * (K_CODE * E_DIM);
    float* onehot = onehot_rep + (size_t)rep * K_CODE;
    int tbase = blockIdx.x * 64 + wave * 16;
    float ds = 0.f;

    for (int j = 0; j < 16; ++j) {
        int t = tbase + j;
        float xv = z_e[(size_t)t * E_DIM + lane];
        int bi = (int)out_ind[t];

        if (flags[t] != 0.f) {
            xs[wave][lane] = xv;  // wave-internal stage; compiler waits lgkm before reads
            float xn_t = xn_ws[t];
            float bestd = INFINITY;
            int besti = 0;
            for (int c = 0; c < 16; ++c) {
                int code = lane + (c << 6);
                const float* wr = embed + (size_t)code * E_DIM;
                float d = 0.f;
#pragma unroll
                for (int i = 0; i < 64; i += 4) {
                    float4 wc = *(const float4*)(wr + i);
                    d = __builtin_fmaf(xs[wave][i + 0], wc.x, d);
                    d = __builtin_fmaf(xs[wave][i + 1], wc.y, d);
                    d = __builtin_fmaf(xs[wave][i + 2], wc.z, d);
                    d = __builtin_fmaf(xs[wave][i + 3], wc.w, d);
                }
                float dist = add_nf(sub_nf(xn_t, d + d), wnorm_ws[code]);
                if (dist < bestd) { bestd = dist; besti = code; }  // ascending in-lane
            }
#pragma unroll
            for (int s = 1; s < 64; s <<= 1) {
                float od = __shfl_xor(bestd, s, 64);
                int oi = __shfl_xor(besti, s, 64);
                if (od < bestd || (od == bestd && oi < besti)) { bestd = od; besti = oi; }
            }
            bi = besti;
            if (lane == 0) out_ind[t] = (float)bi;
        }

        // np order: r = fl(z_q - z_e); out = fl(z_e + r)
        float wv = embed[(size_t)bi * E_DIM + lane];
        float rr = sub_nf(wv, xv);
        out_zq[(size_t)t * E_DIM + lane] = add_nf(xv, rr);
        ds = __builtin_fmaf(rr, rr, ds);

        atomicAdd(&esum[(size_t)bi * E_DIM + lane], xv);  // coalesced 256B row
        if (lane == 0) atomicAdd(&onehot[bi], 1.0f);
    }

#pragma unroll
    for (int o = 32; o > 0; o >>= 1) ds += __shfl_down(ds, o, 64);
    if (lane == 0) atomicAdd(diff_acc, ds);
}

// ncs, n, diff: single block (tiny)
__global__ __launch_bounds__(1024) void finalize_cs_kernel(const float* __restrict__ cluster_size,
                                                           const float* __restrict__ onehot_rep,
                                                           const float* __restrict__ ws_diff,
                                                           float* __restrict__ out_diff,
                                                           float* __restrict__ out_ncs,
                                                           float* __restrict__ ws_n,
                                                           int nrep) {
    int k = threadIdx.x;
    float oh = 0.f;
    for (int r = 0; r < nrep; ++r) oh += onehot_rep[(size_t)r * K_CODE + k];
    float ncs = DECAYF * cluster_size[k] + (1.0f - DECAYF) * oh;
    out_ncs[k] = ncs;

    __shared__ float red[1024];
    red[k] = ncs;
    __syncthreads();
#pragma unroll
    for (int s = 512; s > 0; s >>= 1) {
        if (k < s) red[k] += red[k + s];
        __syncthreads();
    }
    if (k == 0) {
        ws_n[0] = red[0];
        out_diff[0] = ws_diff[0] * (1.0f / 4194304.0f);  // /2^22 exact
    }
}

// embed_avg / embed update spread across 64 blocks
__global__ __launch_bounds__(256) void finalize_embed_kernel(const float* __restrict__ embed_avg,
                                                             const float* __restrict__ esum_rep,
                                                             const float* __restrict__ out_ncs,
                                                             const float* __restrict__ ws_n,
                                                             float* __restrict__ out_ne,
                                                             float* __restrict__ out_nea,
                                                             int nrep) {
    int gid = blockIdx.x * 256 + threadIdx.x;
    int k = gid >> 4;
    int c = gid & 15;
    float n = ws_n[0];
    float ncs = out_ncs[k];
    float cs = (ncs + EPSF) / (n + (float)K_CODE * EPSF) * n;

    size_t off = (size_t)k * E_DIM + (size_t)c * 4;
    float4 s4 = make_float4(0.f, 0.f, 0.f, 0.f);
    for (int r = 0; r < nrep; ++r) {
        float4 v = *reinterpret_cast<const float4*>(esum_rep + (size_t)r * (K_CODE * E_DIM) + off);
        s4.x += v.x; s4.y += v.y; s4.z += v.z; s4.w += v.w;
    }
    float4 a = *reinterpret_cast<const float4*>(embed_avg + off);
    float4 nea, ne;
    nea.x = DECAYF * a.x + (1.0f - DECAYF) * s4.x;
    nea.y = DECAYF * a.y + (1.0f - DECAYF) * s4.y;
    nea.z = DECAYF * a.z + (1.0f - DECAYF) * s4.z;
    nea.w = DECAYF * a.w + (1.0f - DECAYF) * s4.w;
    ne.x = nea.x / cs; ne.y = nea.y / cs; ne.z = nea.z / cs; ne.w = nea.w / cs;
    *reinterpret_cast<float4*>(out_nea + off) = nea;
    *reinterpret_cast<float4*>(out_ne + off) = ne;
}

extern "C" void kernel_launch(void* const* d_in, const int* in_sizes, int n_in,
                              void* d_out, int out_size, void* d_ws, size_t ws_size,
                              hipStream_t stream) {
    const float* z_e = (const float*)d_in[0];
    const float* embed = (const float*)d_in[1];
    const float* cluster_size = (const float*)d_in[2];
    const float* embed_avg = (const float*)d_in[3];

    float* out = (float*)d_out;
    float* o_zq = out;                   // 4194304
    float* o_diff = out + 4194304;       // 1
    float* o_ind = out + 4194305;        // 65536
    float* o_ne = out + 4194305 + 65536; // 65536
    float* o_ncs = o_ne + 65536;         // 1024
    float* o_nea = o_ncs + 1024;         // 65536

    // ws layout (floats), adaptive in nrep:
    // [0,1024) wnorm | [1024] diff | [1025] n | [2048,10240) onehot reps
    // [10240, E) esum reps, E = 10240 + nrep*65536
    // [E, +65536) xn | [+65536, +131072) flags
    // [+131072, +163840) w_hi (ushort) | [+163840, +196608) w_lo (ushort)
    int nrep = 8;
    while (nrep > 1 &&
           ws_size < (size_t)(10240 + (size_t)nrep * 65536 + 196608) * 4) nrep >>= 1;

    float* ws = (float*)d_ws;
    float* ws_wnorm = ws;
    float* ws_diff = ws + 1024;
    float* ws_n = ws + 1025;
    float* ws_onehot = ws + 2048;
    float* ws_esum = ws + 10240;
    size_t esum_end = 10240 + (size_t)nrep * 65536;
    float* ws_xn = ws + esum_end;
    float* ws_flags = ws + esum_end + 65536;
    unsigned short* ws_whi = (unsigned short*)(ws + esum_end + 131072);
    unsigned short* ws_wlo = (unsigned short*)(ws + esum_end + 163840);

    hipMemsetAsync(d_ws, 0, esum_end * sizeof(float), stream);              // diff/n/onehot/esum
    hipMemsetAsync((void*)ws_flags, 0, (size_t)65536 * sizeof(float), stream);  // flags

    prep_kernel<<<260, 256, 0, stream>>>(z_e, embed, ws_xn, ws_wnorm, ws_whi, ws_wlo);
    mfma_argmin_kernel<<<1024, 256, 0, stream>>>(z_e, embed, ws_xn, ws_wnorm,
                                                 ws_whi, ws_wlo, o_ind, ws_flags);
    epilogue_kernel<<<1024, 256, 0, stream>>>(z_e, embed, ws_xn, ws_wnorm, o_ind, ws_flags,
                                              o_zq, ws_diff, ws_esum, ws_onehot, nrep - 1);
    finalize_cs_kernel<<<1, 1024, 0, stream>>>(cluster_size, ws_onehot, ws_diff,
                                               o_diff, o_ncs, ws_n, nrep);
    finalize_embed_kernel<<<64, 256, 0, stream>>>(embed_avg, ws_esum, o_ncs, ws_n,
                                                  o_ne, o_nea, nrep);
}